// Round 5
// baseline (254.725 us; speedup 1.0000x reference)
//
#include <hip/hip_runtime.h>

typedef __attribute__((ext_vector_type(8))) short short8;
typedef __attribute__((ext_vector_type(4))) float float4v;

// fp32 -> bf16, round-to-nearest-even
__device__ inline short f2bf(float f) {
    union { float f; unsigned int u; } c; c.f = f;
    unsigned int u = c.u;
    unsigned int r = (u + 0x7fffu + ((u >> 16) & 1u)) >> 16;
    return (short)r;
}

// async 16B/lane global->LDS (wave-uniform LDS base + lane*16)
__device__ inline void gl2lds16(const short* g, short* l) {
    __builtin_amdgcn_global_load_lds(
        (const __attribute__((address_space(1))) unsigned int*)g,
        (__attribute__((address_space(3))) unsigned int*)l, 16, 0, 0);
}

// Swizzle: bf16 rows of 64 elems, element (row,col) at group (col>>3)^(row&7).
// Rows stay contiguous (async-stage friendly); b128 frag reads 2-way max.

// ---------------------------------------------------------------------------
// Kernel 0: W fp32 [1024][64] x3 -> Wt_s bf16 chunk-major swizzled
// [kchunk 16][n 192][64].
// ---------------------------------------------------------------------------
__global__ __launch_bounds__(256) void wconv_kernel(
    const float* __restrict__ Wq, const float* __restrict__ Wk,
    const float* __restrict__ Wv, short* __restrict__ Wt_s)
{
    __shared__ short Ls[64 * 72];
    const int w  = blockIdx.x >> 4;
    const int c  = blockIdx.x & 15;
    const int k0 = c * 64;
    const float* W = (w == 0) ? Wq : (w == 1) ? Wk : Wv;
    const int tid = threadIdx.x;

#pragma unroll
    for (int i = 0; i < 4; i++) {
        int kk = (tid >> 4) + i * 16;
        int c4 = (tid & 15) * 4;
        float4 v = *(const float4*)&W[(size_t)(k0 + kk) * 64 + c4];
        Ls[kk * 72 + c4 + 0] = f2bf(v.x);
        Ls[kk * 72 + c4 + 1] = f2bf(v.y);
        Ls[kk * 72 + c4 + 2] = f2bf(v.z);
        Ls[kk * 72 + c4 + 3] = f2bf(v.w);
    }
    __syncthreads();
    const int n  = tid >> 2;
    const int k8 = (tid & 3) * 16;
    short8 o0, o1;
#pragma unroll
    for (int j = 0; j < 8; j++) o0[j] = Ls[(k8 + j) * 72 + n];
#pragma unroll
    for (int j = 0; j < 8; j++) o1[j] = Ls[(k8 + 8 + j) * 72 + n];
    const int gn = w * 64 + n;
    short* base = &Wt_s[((size_t)c * 192 + gn) * 64];
    int g0 = k8 >> 3;
    *(short8*)&base[((g0    ) ^ (gn & 7)) * 8] = o0;
    *(short8*)&base[((g0 + 1) ^ (gn & 7)) * 8] = o1;
}

// ---------------------------------------------------------------------------
// Kernel 1: fused QKV projection with register-held fragment pipeline.
// 1024 blocks x 256 thr (4 blocks/CU). Block = 32 M x 192 N; wave = 32M x 48N.
// Loop: barrier -> issue A-global + async-B (i+1) -> MFMA(i) on regs ->
// convert/store A -> barrier -> frag-read(i+1). Staging latency overlaps MFMA.
// ---------------------------------------------------------------------------
__global__ __launch_bounds__(256) void qkv_kernel(
    const float* __restrict__ x, const short* __restrict__ Wt_s,
    short* __restrict__ qo, short* __restrict__ k_s, short* __restrict__ vT_t)
{
    __shared__ short As[32 * 72];
    __shared__ short Bs[192 * 64];

    const int tid  = threadIdx.x;
    const int wave = tid >> 6, lane = tid & 63;
    const int quad = lane >> 4, l16 = lane & 15;
    const int m0   = blockIdx.x * 32;

    float4v acc[2][3];
#pragma unroll
    for (int mf = 0; mf < 2; mf++)
#pragma unroll
        for (int nt = 0; nt < 3; nt++) acc[mf][nt] = (float4v)0.0f;

    const int arow = tid >> 3;
    const int acol = (tid & 7) * 8;
    const float* ap = &x[(size_t)(m0 + arow) * 1024 + acol];
    const int lofs = lane * 8;
    short* bdst = &Bs[wave * 48 * 64];

    short8 ra[2][2], rb[2][3];
    float4 ax0, ax1;

    // ---- prologue: stage chunk 0, then preload frags ----
    ax0 = *(const float4*)(ap + 0);
    ax1 = *(const float4*)(ap + 4);
    {
        const short* gs = Wt_s + ((size_t)0 * 192 + wave * 48) * 64;
#pragma unroll
        for (int i = 0; i < 6; i++)
            gl2lds16(gs + i * 512 + lofs, bdst + i * 512 + lofs);
    }
    {
        short8 av;
        av[0]=f2bf(ax0.x); av[1]=f2bf(ax0.y); av[2]=f2bf(ax0.z); av[3]=f2bf(ax0.w);
        av[4]=f2bf(ax1.x); av[5]=f2bf(ax1.y); av[6]=f2bf(ax1.z); av[7]=f2bf(ax1.w);
        *(short8*)&As[arow * 72 + acol] = av;
    }
    __syncthreads();
#pragma unroll
    for (int kc2 = 0; kc2 < 2; kc2++) {
        ra[kc2][0] = *(const short8*)&As[(l16)      * 72 + kc2*32 + quad*8];
        ra[kc2][1] = *(const short8*)&As[(16 + l16) * 72 + kc2*32 + quad*8];
#pragma unroll
        for (int nt = 0; nt < 3; nt++) {
            int brow = wave * 48 + nt * 16 + l16;
            rb[kc2][nt] = *(const short8*)&Bs[brow * 64 + (((kc2*4 + quad)) ^ (brow & 7)) * 8];
        }
    }

    for (int kc = 0; kc < 1024; kc += 64) {
        const bool notlast = (kc < 960);
        __syncthreads();                       // frag reads drained -> LDS reusable
        if (notlast) {
            ax0 = *(const float4*)(ap + kc + 64);
            ax1 = *(const float4*)(ap + kc + 68);
            const short* gs = Wt_s + ((size_t)((kc >> 6) + 1) * 192 + wave * 48) * 64;
#pragma unroll
            for (int i = 0; i < 6; i++)
                gl2lds16(gs + i * 512 + lofs, bdst + i * 512 + lofs);
        }
        // MFMA on current regs (overlaps in-flight staging)
#pragma unroll
        for (int kc2 = 0; kc2 < 2; kc2++)
#pragma unroll
            for (int nt = 0; nt < 3; nt++) {
                acc[0][nt] = __builtin_amdgcn_mfma_f32_16x16x32_bf16(ra[kc2][0], rb[kc2][nt], acc[0][nt], 0, 0, 0);
                acc[1][nt] = __builtin_amdgcn_mfma_f32_16x16x32_bf16(ra[kc2][1], rb[kc2][nt], acc[1][nt], 0, 0, 0);
            }
        if (notlast) {
            short8 av;
            av[0]=f2bf(ax0.x); av[1]=f2bf(ax0.y); av[2]=f2bf(ax0.z); av[3]=f2bf(ax0.w);
            av[4]=f2bf(ax1.x); av[5]=f2bf(ax1.y); av[6]=f2bf(ax1.z); av[7]=f2bf(ax1.w);
            *(short8*)&As[arow * 72 + acol] = av;
        }
        __syncthreads();                       // staging visible
        if (notlast) {
#pragma unroll
            for (int kc2 = 0; kc2 < 2; kc2++) {
                ra[kc2][0] = *(const short8*)&As[(l16)      * 72 + kc2*32 + quad*8];
                ra[kc2][1] = *(const short8*)&As[(16 + l16) * 72 + kc2*32 + quad*8];
#pragma unroll
                for (int nt = 0; nt < 3; nt++) {
                    int brow = wave * 48 + nt * 16 + l16;
                    rb[kc2][nt] = *(const short8*)&Bs[brow * 64 + (((kc2*4 + quad)) ^ (brow & 7)) * 8];
                }
            }
        }
    }
    // epilogue: C/D col=l16, row=quad*4+r
#pragma unroll
    for (int mf = 0; mf < 2; mf++) {
#pragma unroll
        for (int nt = 0; nt < 3; nt++) {
            int g = wave * 48 + nt * 16 + l16;
#pragma unroll
            for (int r = 0; r < 4; r++) {
                int row = m0 + mf * 16 + quad * 4 + r;
                short val = f2bf(acc[mf][nt][r]);
                if (g < 64) {
                    qo[(size_t)row * 64 + g] = val;
                } else if (g < 128) {
                    int h = g - 64;
                    k_s[(size_t)row * 64 + (((h >> 3) ^ (row & 7)) * 8 + (h & 7))] = val;
                } else {
                    int h = g - 128;
                    int bb = row >> 11, tt = row & 2047;
                    int tc = tt >> 6, tl = tt & 63;
                    vT_t[(((size_t)bb * 32 + tc) * 64 + h) * 64 +
                         (((tl >> 3) ^ (h & 7)) * 8 + (tl & 7))] = val;
                }
            }
        }
    }
}

// ---------------------------------------------------------------------------
// Kernel 2: flash attention, causal, D=64, scale 1/32 in exp2, no max-sub.
// 1024 blocks x 128 thr (4 blocks/CU, LDS exactly 40 KB). KV tiles of 128:
// half the barriers of R4, 32 MFMA/wave per drain. Heavy/light qt paired.
// ---------------------------------------------------------------------------
#define SCALE_LOG2E 0.04508422132f   // (1/32) * log2(e)

__global__ __launch_bounds__(128) void attn_kernel(
    const short* __restrict__ q, const short* __restrict__ k_s,
    const short* __restrict__ vT_t, float* __restrict__ out)
{
    __shared__ short Ks[128 * 64];   // [s][64sw]           16 KB
    __shared__ short Vs[2 * 64 * 64];// [chunk][d][64sw]    16 KB
    __shared__ short Ps[32 * 128];   // [m][128 sw]          8 KB

    const int tid  = threadIdx.x;
    const int wave = tid >> 6, lane = tid & 63;
    const int quad = lane >> 4, l16 = lane & 15;

    int b, qt;                       // qt = 32-row Q block index (0..63)
    if (blockIdx.x < 512) { b = blockIdx.x >> 5; qt = 32 + (blockIdx.x & 31); }
    else { int t2 = blockIdx.x - 512; b = t2 >> 5; qt = 31 - (t2 & 31); }

    const short* kb = k_s  + (size_t)b * 2048 * 64;
    const short* vb = vT_t + (size_t)b * 32 * 64 * 64;

    const short* qrow = q + ((size_t)b * 2048 + qt*32 + wave*16 + l16) * 64;
    short8 qf0 = *(const short8*)&qrow[quad*8];
    short8 qf1 = *(const short8*)&qrow[32 + quad*8];

    float4v oacc[4];
#pragma unroll
    for (int t = 0; t < 4; t++) oacc[t] = (float4v)0.0f;
    float l_i[4] = {0.f, 0.f, 0.f, 0.f};

    const int tg   = qt*32 + wave*16 + quad*4;
    const int jmax = qt >> 2;
    const int lofs = lane * 8;
    const int psw  = l16 & 7;        // row&7 for this lane's P A-frag rows

    for (int j = 0; j <= jmax; j++) {
        __syncthreads();
        // K rows j*128..+127 (wave halves, contiguous swizzled source)
        const short* kg = kb + ((size_t)j * 128 + wave * 64) * 64;
        short* kl = &Ks[wave * 64 * 64];
#pragma unroll
        for (int i = 0; i < 8; i++)
            gl2lds16(kg + i * 512 + lofs, kl + i * 512 + lofs);
        // V chunks 2j+wave (each contiguous 8 KB)
        const short* vg = vb + (size_t)(2*j + wave) * 4096;
        short* vl = &Vs[wave * 4096];
#pragma unroll
        for (int i = 0; i < 8; i++)
            gl2lds16(vg + i * 512 + lofs, vl + i * 512 + lofs);
        __syncthreads();

        // --- S = Q K^T : 8 col-tiles of 16 ---
        float4v sacc[8];
#pragma unroll
        for (int t = 0; t < 8; t++) sacc[t] = (float4v)0.0f;
#pragma unroll
        for (int t = 0; t < 8; t++) {
            int brow = t*16 + l16;
            short8 b0 = *(const short8*)&Ks[brow * 64 + ((    quad) ^ (brow & 7)) * 8];
            short8 b1 = *(const short8*)&Ks[brow * 64 + ((4 + quad) ^ (brow & 7)) * 8];
            sacc[t] = __builtin_amdgcn_mfma_f32_16x16x32_bf16(qf0, b0, sacc[t], 0, 0, 0);
            sacc[t] = __builtin_amdgcn_mfma_f32_16x16x32_bf16(qf1, b1, sacc[t], 0, 0, 0);
        }
        // --- p = exp2(s*c); mask only on final tile ---
        if (j == jmax) {
#pragma unroll
            for (int t = 0; t < 8; t++) {
                int sg = j*128 + t*16 + l16;
#pragma unroll
                for (int r = 0; r < 4; r++) {
                    float p = exp2f(sacc[t][r] * SCALE_LOG2E);
                    if (sg > tg + r) p = 0.0f;
                    sacc[t][r] = p;
                    l_i[r] += p;
                }
            }
        } else {
#pragma unroll
            for (int t = 0; t < 8; t++)
#pragma unroll
                for (int r = 0; r < 4; r++) {
                    float p = exp2f(sacc[t][r] * SCALE_LOG2E);
                    sacc[t][r] = p;
                    l_i[r] += p;
                }
        }
        // --- P (C-layout) -> swizzled LDS -> A-layout ---
#pragma unroll
        for (int t = 0; t < 8; t++)
#pragma unroll
            for (int r = 0; r < 4; r++) {
                int m = wave*16 + quad*4 + r;
                int grp = (t*2 + (l16 >> 3)) ^ ((quad*4 + r) & 7);
                Ps[m * 128 + grp * 8 + (l16 & 7)] = f2bf(sacc[t][r]);
            }
        // --- O += P V : 4 K-chunks of 32 ---
#pragma unroll
        for (int kc = 0; kc < 4; kc++) {
            short8 af = *(const short8*)&Ps[(wave*16 + l16) * 128 + ((kc*4 + quad) ^ psw) * 8];
#pragma unroll
            for (int t = 0; t < 4; t++) {
                int drow = t*16 + l16;
                short8 bf = *(const short8*)&Vs[(kc >> 1) * 4096 + drow * 64 +
                                                (((kc & 1)*4 + quad) ^ (drow & 7)) * 8];
                oacc[t] = __builtin_amdgcn_mfma_f32_16x16x32_bf16(af, bf, oacc[t], 0, 0, 0);
            }
        }
    }
#pragma unroll
    for (int off = 1; off < 16; off <<= 1)
#pragma unroll
        for (int r = 0; r < 4; r++)
            l_i[r] += __shfl_xor(l_i[r], off, 64);
#pragma unroll
    for (int r = 0; r < 4; r++) {
        float inv = 1.0f / l_i[r];
        int row = qt*32 + wave*16 + quad*4 + r;
#pragma unroll
        for (int t = 0; t < 4; t++)
            out[((size_t)b * 2048 + row) * 64 + t*16 + l16] = oacc[t][r] * inv;
    }
}

extern "C" void kernel_launch(void* const* d_in, const int* in_sizes, int n_in,
                              void* d_out, int out_size, void* d_ws, size_t ws_size,
                              hipStream_t stream)
{
    const float* x  = (const float*)d_in[0];
    const float* Wq = (const float*)d_in[1];
    const float* Wk = (const float*)d_in[2];
    const float* Wv = (const float*)d_in[3];

    short* qw   = (short*)d_ws;                     // bf16 [32768,64] natural
    short* ks   = qw + (size_t)32768 * 64;          // bf16 [32768,64] swizzled
    short* vTt  = ks + (size_t)32768 * 64;          // bf16 [16][32][64][64sw]
    short* Wts  = vTt + (size_t)32768 * 64;         // bf16 [16][192][64sw]
    float* out  = (float*)d_out;

    hipLaunchKernelGGL(wconv_kernel, dim3(48), dim3(256), 0, stream,
                       Wq, Wk, Wv, Wts);
    hipLaunchKernelGGL(qkv_kernel, dim3(1024), dim3(256), 0, stream,
                       x, Wts, qw, ks, vTt);
    hipLaunchKernelGGL(attn_kernel, dim3(1024), dim3(128), 0, stream,
                       qw, ks, vTt, out);
}